// Round 3
// baseline (733.445 us; speedup 1.0000x reference)
//
#include <hip/hip_runtime.h>
#include <math.h>

#define NB 2048
#define NS 512
#define ND 96

typedef __attribute__((ext_vector_type(8))) short short8;
typedef __attribute__((ext_vector_type(4))) float floatx4;

__device__ __forceinline__ unsigned f2bfu(float f) {
    union { float f; unsigned u; } c; c.f = f;
    unsigned u = c.u;
    u += 0x7FFF + ((u >> 16) & 1);   // RNE
    return u >> 16;
}
__device__ __forceinline__ float sigm(float x) {
    return 1.0f / (1.0f + __expf(-x));
}
__device__ __forceinline__ short8 cvt8(floatx4 p0, floatx4 p1) {
    short8 v;
    v[0]=(short)f2bfu(p0[0]); v[1]=(short)f2bfu(p0[1]);
    v[2]=(short)f2bfu(p0[2]); v[3]=(short)f2bfu(p0[3]);
    v[4]=(short)f2bfu(p1[0]); v[5]=(short)f2bfu(p1[1]);
    v[6]=(short)f2bfu(p1[2]); v[7]=(short)f2bfu(p1[3]);
    return v;
}

__global__ __launch_bounds__(512, 4)
void attn_fused(const float* __restrict__ seq,   // (B,S,96)
                const float* __restrict__ tgt,   // (B,1,96)
                const int*   __restrict__ mask,  // (B,513,1) int32
                const float* __restrict__ w1,    // (96,96) [e][d]
                const float* __restrict__ b1,    // (96)
                const float* __restrict__ w2,    // (96,96) [e][d]
                const float* __restrict__ b2,    // (96)
                float* __restrict__ out)         // (B,96)
{
    // W1 staged as bf16 MFMA B-fragments: frag(t,kk) for lane L at
    // w1f[((t*3+kk)*64 + L)*8 .. +8]  — ds_read_b128, conflict-free.
    __shared__ short w1f[18 * 64 * 8];           // 18 KB
    __shared__ floatx4 thp4[ND];                 // tgt_h K-partials [e]
    __shared__ float maskf[NS];                  // 1.0 = keep, 0.0 = masked
    __shared__ float red2[8];
    __shared__ float osum[8][ND];                // per-wave output partials

    const int b    = blockIdx.x;
    const int tid  = threadIdx.x;
    const int lane = tid & 63;
    const int wave = tid >> 6;
    const int l15  = lane & 15;
    const int quad = lane >> 4;

    // ---- mask -> LDS as multiplicative 0/1 float (coalesced, s = tid) ----
    maskf[tid] = (mask[(size_t)b * (NS + 1) + tid] != 0) ? 0.0f : 1.0f;

    // ---- stage W1 -> bf16 fragments in LDS ----
    for (int idx = tid; idx < 1152; idx += 512) {   // 96 rows x 12 chunks of 8
        const int e  = idx / 12;
        const int dc = idx - 12 * e;
        const int kk = dc >> 2;
        const int q  = dc & 3;
        const float* p = w1 + e * ND + kk * 32 + q * 8;
        floatx4 p0 = *(const floatx4*)(p);
        floatx4 p1 = *(const floatx4*)(p + 4);
        const int t = e >> 4, r = e & 15;
        *(short8*)&w1f[(((t * 3 + kk) * 64) + q * 16 + r) * 8] = cvt8(p0, p1);
    }

    // ---- tgt_h partials: 384 threads, e = tid>>2, K-quarter = tid&3 ----
    if (tid < 4 * ND) {
        const int e    = tid >> 2;
        const int part = tid & 3;
        const float* tv = tgt + (size_t)b * ND + part * 24;
        const float* wr = w2 + e * ND + part * 24;
        float acc = 0.f;
        #pragma unroll
        for (int d = 0; d < 24; d += 4) {
            floatx4 a = *(const floatx4*)(tv + d);
            floatx4 w = *(const floatx4*)(wr + d);
            acc += a[0]*w[0] + a[1]*w[1] + a[2]*w[2] + a[3]*w[3];
        }
        thp4[e][part] = acc;
    }
    __syncthreads();

    float tgtv[6], biasv[6];
    #pragma unroll
    for (int t = 0; t < 6; ++t) {
        const int e = 16 * t + l15;
        floatx4 tp = thp4[e];
        tgtv[t]  = b2[e] + tp[0] + tp[1] + tp[2] + tp[3];
        biasv[t] = b1[e];
    }

    // ---- fully fused main loop: each of 8 waves owns 4 s-tiles of 16 rows.
    // Per tile: seq_h via MFMA (fp32 in acc6), scores via sigmoid-sum +
    // quad butterfly, unnormalized weights e0 = maskf * exp(score-48)
    // (fixed shift; softmax is shift-invariant, scores in (0,96)), and the
    // weighted-output accumulation — no persistent per-tile state survives
    // the loop, so nothing can spill.
    const float* abase = seq + ((size_t)b * NS + l15) * ND + quad * 8;
    float o_acc[6] = {0.f, 0.f, 0.f, 0.f, 0.f, 0.f};
    float sacc = 0.f;      // Σ e0 over this quad's rows (dup across l15)

    #pragma unroll
    for (int sti = 0; sti < 4; ++sti) {
        const int s0 = (wave * 4 + sti) * 16;
        short8 af[3];
        #pragma unroll
        for (int kk = 0; kk < 3; ++kk) {
            const float* p = abase + (size_t)s0 * ND + kk * 32;
            af[kk] = cvt8(*(const floatx4*)(p), *(const floatx4*)(p + 4));
        }
        floatx4 acc6[6];
        float p0s = 0.f, p1s = 0.f, p2s = 0.f, p3s = 0.f;
        #pragma unroll
        for (int t = 0; t < 6; ++t) {
            floatx4 acc = { biasv[t], biasv[t], biasv[t], biasv[t] };
            #pragma unroll
            for (int kk = 0; kk < 3; ++kk) {
                const short8 bf = *(const short8*)&w1f[((t * 3 + kk) * 64 + lane) * 8];
                acc = __builtin_amdgcn_mfma_f32_16x16x32_bf16(af[kk], bf, acc, 0, 0, 0);
            }
            acc6[t] = acc;
            const float thv = tgtv[t];
            p0s += sigm(acc[0] + thv);
            p1s += sigm(acc[1] + thv);
            p2s += sigm(acc[2] + thv);
            p3s += sigm(acc[3] + thv);
        }
        // reduce over the 16 lanes (e-columns) of each quad; butterfly
        // leaves the full score in every lane of the quad
        #pragma unroll
        for (int off = 1; off < 16; off <<= 1) {
            p0s += __shfl_xor(p0s, off, 64);
            p1s += __shfl_xor(p1s, off, 64);
            p2s += __shfl_xor(p2s, off, 64);
            p3s += __shfl_xor(p3s, off, 64);
        }
        // unnormalized softmax weights for this quad's 4 rows
        const int sq = s0 + quad * 4;
        const float e0 = maskf[sq + 0] * __expf(p0s - 48.f);
        const float e1 = maskf[sq + 1] * __expf(p1s - 48.f);
        const float e2 = maskf[sq + 2] * __expf(p2s - 48.f);
        const float e3 = maskf[sq + 3] * __expf(p3s - 48.f);
        sacc += e0 + e1 + e2 + e3;
        #pragma unroll
        for (int t = 0; t < 6; ++t) {
            o_acc[t] += e0 * acc6[t][0] + e1 * acc6[t][1]
                      + e2 * acc6[t][2] + e3 * acc6[t][3];
        }
    }

    // ---- denominator: sacc is identical across the 16 l15 lanes of a quad;
    // xor-16/32 sums the 4 quads exactly once ----
    float ss = sacc;
    ss += __shfl_xor(ss, 16, 64);
    ss += __shfl_xor(ss, 32, 64);
    if (lane == 0) red2[wave] = ss;
    __syncthreads();
    float tot = red2[0];
    #pragma unroll
    for (int w = 1; w < 8; ++w) tot += red2[w];

    // ---- output reduce: sum quads in-wave, then waves via LDS ----
    #pragma unroll
    for (int t = 0; t < 6; ++t) {
        o_acc[t] += __shfl_xor(o_acc[t], 16, 64);
        o_acc[t] += __shfl_xor(o_acc[t], 32, 64);
    }
    if (quad == 0) {
        #pragma unroll
        for (int t = 0; t < 6; ++t) osum[wave][16 * t + l15] = o_acc[t];
    }
    __syncthreads();
    if (tid < ND) {
        float a = 0.f;
        #pragma unroll
        for (int w = 0; w < 8; ++w) a += osum[w][tid];
        out[(size_t)b * ND + tid] = a * (1.0f / tot);
    }
}

extern "C" void kernel_launch(void* const* d_in, const int* in_sizes, int n_in,
                              void* d_out, int out_size, void* d_ws, size_t ws_size,
                              hipStream_t stream) {
    const float* seq  = (const float*)d_in[0];
    const float* tgt  = (const float*)d_in[1];
    const int*   mask = (const int*)d_in[2];
    const float* w1   = (const float*)d_in[3];
    const float* b1   = (const float*)d_in[4];
    const float* w2   = (const float*)d_in[5];
    const float* b2   = (const float*)d_in[6];
    float* out = (float*)d_out;
    attn_fused<<<dim3(NB), dim3(512), 0, stream>>>(seq, tgt, mask, w1, b1, w2, b2, out);
}

// Round 4
// 603.466 us; speedup vs baseline: 1.2154x; 1.2154x over previous
//
#include <hip/hip_runtime.h>
#include <math.h>

#define NB 2048
#define NS 512
#define ND 96

typedef __attribute__((ext_vector_type(8))) short short8;
typedef __attribute__((ext_vector_type(4))) float floatx4;

__device__ __forceinline__ unsigned f2bfu(float f) {
    union { float f; unsigned u; } c; c.f = f;
    unsigned u = c.u;
    u += 0x7FFF + ((u >> 16) & 1);   // RNE
    return u >> 16;
}
__device__ __forceinline__ float sigm(float x) {
    return 1.0f / (1.0f + __expf(-x));
}
__device__ __forceinline__ short8 cvt8(floatx4 p0, floatx4 p1) {
    short8 v;
    v[0]=(short)f2bfu(p0[0]); v[1]=(short)f2bfu(p0[1]);
    v[2]=(short)f2bfu(p0[2]); v[3]=(short)f2bfu(p0[3]);
    v[4]=(short)f2bfu(p1[0]); v[5]=(short)f2bfu(p1[1]);
    v[6]=(short)f2bfu(p1[2]); v[7]=(short)f2bfu(p1[3]);
    return v;
}

// NOTE: on this toolchain the 2nd launch_bounds arg empirically sets the
// VGPR cap as if it were blocks/CU: (512,4)->64 regs (spill!), (512,3)->84
// (spill!). (512,2) -> 128-reg cap: honest peak pressure ~100, no spill.
__global__ __launch_bounds__(512, 2)
void attn_fused(const float* __restrict__ seq,   // (B,S,96)
                const float* __restrict__ tgt,   // (B,1,96)
                const int*   __restrict__ mask,  // (B,513,1) int32
                const float* __restrict__ w1,    // (96,96) [e][d]
                const float* __restrict__ b1,    // (96)
                const float* __restrict__ w2,    // (96,96) [e][d]
                const float* __restrict__ b2,    // (96)
                float* __restrict__ out)         // (B,96)
{
    // W1 staged as bf16 MFMA B-fragments: frag(t,kk) for lane L at
    // w1f[((t*3+kk)*64 + L)*8 .. +8]  — ds_read_b128, conflict-free.
    __shared__ short w1f[18 * 64 * 8];           // 18 KB
    __shared__ floatx4 thp4[ND];                 // tgt_h K-partials [e]
    __shared__ float maskf[NS];                  // 1.0 = keep, 0.0 = masked
    __shared__ float red2[8];
    __shared__ float osum[8][ND];                // per-wave output partials

    const int b    = blockIdx.x;
    const int tid  = threadIdx.x;
    const int lane = tid & 63;
    const int wave = tid >> 6;
    const int l15  = lane & 15;
    const int quad = lane >> 4;

    // ---- mask -> LDS as multiplicative 0/1 float (coalesced, s = tid) ----
    maskf[tid] = (mask[(size_t)b * (NS + 1) + tid] != 0) ? 0.0f : 1.0f;

    // ---- stage W1 -> bf16 fragments in LDS ----
    for (int idx = tid; idx < 1152; idx += 512) {   // 96 rows x 12 chunks of 8
        const int e  = idx / 12;
        const int dc = idx - 12 * e;
        const int kk = dc >> 2;
        const int q  = dc & 3;
        const float* p = w1 + e * ND + kk * 32 + q * 8;
        floatx4 p0 = *(const floatx4*)(p);
        floatx4 p1 = *(const floatx4*)(p + 4);
        const int t = e >> 4, r = e & 15;
        *(short8*)&w1f[(((t * 3 + kk) * 64) + q * 16 + r) * 8] = cvt8(p0, p1);
    }

    // ---- tgt_h partials: 384 threads, e = tid>>2, K-quarter = tid&3 ----
    if (tid < 4 * ND) {
        const int e    = tid >> 2;
        const int part = tid & 3;
        const float* tv = tgt + (size_t)b * ND + part * 24;
        const float* wr = w2 + e * ND + part * 24;
        float acc = 0.f;
        #pragma unroll
        for (int d = 0; d < 24; d += 4) {
            floatx4 a = *(const floatx4*)(tv + d);
            floatx4 w = *(const floatx4*)(wr + d);
            acc += a[0]*w[0] + a[1]*w[1] + a[2]*w[2] + a[3]*w[3];
        }
        thp4[e][part] = acc;
    }
    __syncthreads();

    float tgtv[6], biasv[6];
    #pragma unroll
    for (int t = 0; t < 6; ++t) {
        const int e = 16 * t + l15;
        floatx4 tp = thp4[e];
        tgtv[t]  = b2[e] + tp[0] + tp[1] + tp[2] + tp[3];
        biasv[t] = b1[e];
    }

    // ---- fully fused main loop: each of 8 waves owns 4 s-tiles of 16 rows.
    // Per tile: seq_h via MFMA (fp32 in acc6), scores via sigmoid-sum +
    // quad butterfly, unnormalized weights e0 = maskf * exp(score-48)
    // (fixed shift; softmax is shift-invariant, scores in (0,96)), and the
    // weighted-output accumulation — no persistent per-tile state survives
    // the loop.
    const float* abase = seq + ((size_t)b * NS + l15) * ND + quad * 8;
    float o_acc[6] = {0.f, 0.f, 0.f, 0.f, 0.f, 0.f};
    float sacc = 0.f;      // Σ e0 over this quad's rows (dup across l15)

    #pragma unroll
    for (int sti = 0; sti < 4; ++sti) {
        const int s0 = (wave * 4 + sti) * 16;
        short8 af[3];
        #pragma unroll
        for (int kk = 0; kk < 3; ++kk) {
            const float* p = abase + (size_t)s0 * ND + kk * 32;
            af[kk] = cvt8(*(const floatx4*)(p), *(const floatx4*)(p + 4));
        }
        floatx4 acc6[6];
        float p0s = 0.f, p1s = 0.f, p2s = 0.f, p3s = 0.f;
        #pragma unroll
        for (int t = 0; t < 6; ++t) {
            floatx4 acc = { biasv[t], biasv[t], biasv[t], biasv[t] };
            #pragma unroll
            for (int kk = 0; kk < 3; ++kk) {
                const short8 bf = *(const short8*)&w1f[((t * 3 + kk) * 64 + lane) * 8];
                acc = __builtin_amdgcn_mfma_f32_16x16x32_bf16(af[kk], bf, acc, 0, 0, 0);
            }
            acc6[t] = acc;
            const float thv = tgtv[t];
            p0s += sigm(acc[0] + thv);
            p1s += sigm(acc[1] + thv);
            p2s += sigm(acc[2] + thv);
            p3s += sigm(acc[3] + thv);
        }
        // reduce over the 16 lanes (e-columns) of each quad; butterfly
        // leaves the full score in every lane of the quad
        #pragma unroll
        for (int off = 1; off < 16; off <<= 1) {
            p0s += __shfl_xor(p0s, off, 64);
            p1s += __shfl_xor(p1s, off, 64);
            p2s += __shfl_xor(p2s, off, 64);
            p3s += __shfl_xor(p3s, off, 64);
        }
        // unnormalized softmax weights for this quad's 4 rows
        const int sq = s0 + quad * 4;
        const float e0 = maskf[sq + 0] * __expf(p0s - 48.f);
        const float e1 = maskf[sq + 1] * __expf(p1s - 48.f);
        const float e2 = maskf[sq + 2] * __expf(p2s - 48.f);
        const float e3 = maskf[sq + 3] * __expf(p3s - 48.f);
        sacc += e0 + e1 + e2 + e3;
        #pragma unroll
        for (int t = 0; t < 6; ++t) {
            o_acc[t] += e0 * acc6[t][0] + e1 * acc6[t][1]
                      + e2 * acc6[t][2] + e3 * acc6[t][3];
        }
    }

    // ---- denominator: sacc is identical across the 16 l15 lanes of a quad;
    // xor-16/32 sums the 4 quads exactly once ----
    float ss = sacc;
    ss += __shfl_xor(ss, 16, 64);
    ss += __shfl_xor(ss, 32, 64);
    if (lane == 0) red2[wave] = ss;
    __syncthreads();
    float tot = red2[0];
    #pragma unroll
    for (int w = 1; w < 8; ++w) tot += red2[w];

    // ---- output reduce: sum quads in-wave, then waves via LDS ----
    #pragma unroll
    for (int t = 0; t < 6; ++t) {
        o_acc[t] += __shfl_xor(o_acc[t], 16, 64);
        o_acc[t] += __shfl_xor(o_acc[t], 32, 64);
    }
    if (quad == 0) {
        #pragma unroll
        for (int t = 0; t < 6; ++t) osum[wave][16 * t + l15] = o_acc[t];
    }
    __syncthreads();
    if (tid < ND) {
        float a = 0.f;
        #pragma unroll
        for (int w = 0; w < 8; ++w) a += osum[w][tid];
        out[(size_t)b * ND + tid] = a * (1.0f / tot);
    }
}

extern "C" void kernel_launch(void* const* d_in, const int* in_sizes, int n_in,
                              void* d_out, int out_size, void* d_ws, size_t ws_size,
                              hipStream_t stream) {
    const float* seq  = (const float*)d_in[0];
    const float* tgt  = (const float*)d_in[1];
    const int*   mask = (const int*)d_in[2];
    const float* w1   = (const float*)d_in[3];
    const float* b1   = (const float*)d_in[4];
    const float* w2   = (const float*)d_in[5];
    const float* b2   = (const float*)d_in[6];
    float* out = (float*)d_out;
    attn_fused<<<dim3(NB), dim3(512), 0, stream>>>(seq, tgt, mask, w1, b1, w2, b2, out);
}

// Round 5
// 595.395 us; speedup vs baseline: 1.2319x; 1.0136x over previous
//
#include <hip/hip_runtime.h>
#include <math.h>

#define NB 2048
#define NS 512
#define ND 96

typedef __attribute__((ext_vector_type(8))) short short8;
typedef __attribute__((ext_vector_type(4))) float floatx4;

__device__ __forceinline__ float sigm(float x) {
    return 1.0f / (1.0f + __expf(-x));
}
// fp32x8 -> bf16x8 via hardware packed convert (RNE), 4 instructions.
__device__ __forceinline__ short8 cvt8(floatx4 p0, floatx4 p1) {
    union { unsigned u[4]; short8 s; } r;
    asm("v_cvt_pk_bf16_f32 %0, %1, %2" : "=v"(r.u[0]) : "v"(p0[0]), "v"(p0[1]));
    asm("v_cvt_pk_bf16_f32 %0, %1, %2" : "=v"(r.u[1]) : "v"(p0[2]), "v"(p0[3]));
    asm("v_cvt_pk_bf16_f32 %0, %1, %2" : "=v"(r.u[2]) : "v"(p1[0]), "v"(p1[1]));
    asm("v_cvt_pk_bf16_f32 %0, %1, %2" : "=v"(r.u[3]) : "v"(p1[2]), "v"(p1[3]));
    return r.s;
}

// NOTE: on this toolchain the 2nd launch_bounds arg empirically sets the
// VGPR cap as 512/(8*N/4): (512,4)->64 regs (spill!), (512,3)->84 (spill!),
// (512,2)->cap ~256: honest peak pressure ~110-130, no spill. Keep (512,2).
__global__ __launch_bounds__(512, 2)
void attn_fused(const float* __restrict__ seq,   // (B,S,96)
                const float* __restrict__ tgt,   // (B,1,96)
                const int*   __restrict__ mask,  // (B,513,1) int32
                const float* __restrict__ w1,    // (96,96) [e][d]
                const float* __restrict__ b1,    // (96)
                const float* __restrict__ w2,    // (96,96) [e][d]
                const float* __restrict__ b2,    // (96)
                float* __restrict__ out)         // (B,96)
{
    // W1 staged as bf16 MFMA B-fragments: frag(t,kk) for lane L at
    // w1f[((t*3+kk)*64 + L)*8 .. +8]  — ds_read_b128, conflict-free.
    __shared__ short w1f[18 * 64 * 8];           // 18 KB
    __shared__ floatx4 thp4[ND];                 // tgt_h K-partials [e]
    __shared__ float maskf[NS];                  // 1.0 = keep, 0.0 = masked
    __shared__ float red2[8];
    __shared__ float osum[8][ND];                // per-wave output partials

    const int b    = blockIdx.x;
    const int tid  = threadIdx.x;
    const int lane = tid & 63;
    const int wave = tid >> 6;
    const int l15  = lane & 15;
    const int quad = lane >> 4;

    // ---- mask -> LDS as multiplicative 0/1 float (coalesced, s = tid) ----
    maskf[tid] = (mask[(size_t)b * (NS + 1) + tid] != 0) ? 0.0f : 1.0f;

    // ---- prologue: issue tile-0 seq loads NOW so the ~900-cyc HBM latency
    // hides under W1 staging + tgt_h + barrier (safe: 256-reg cap) ----
    const float* abase = seq + ((size_t)b * NS + l15) * ND + quad * 8;
    floatx4 pre[6];
    {
        const float* p = abase + (size_t)(wave * 64) * ND;   // tile 0 s0=wave*64
        #pragma unroll
        for (int kk = 0; kk < 3; ++kk) {
            pre[2 * kk]     = *(const floatx4*)(p + kk * 32);
            pre[2 * kk + 1] = *(const floatx4*)(p + kk * 32 + 4);
        }
    }

    // ---- stage W1 -> bf16 fragments in LDS ----
    for (int idx = tid; idx < 1152; idx += 512) {   // 96 rows x 12 chunks of 8
        const int e  = idx / 12;
        const int dc = idx - 12 * e;
        const int kk = dc >> 2;
        const int q  = dc & 3;
        const float* p = w1 + e * ND + kk * 32 + q * 8;
        floatx4 p0 = *(const floatx4*)(p);
        floatx4 p1 = *(const floatx4*)(p + 4);
        const int t = e >> 4, r = e & 15;
        *(short8*)&w1f[(((t * 3 + kk) * 64) + q * 16 + r) * 8] = cvt8(p0, p1);
    }

    // ---- tgt_h partials: 384 threads, e = tid>>2, K-quarter = tid&3 ----
    if (tid < 4 * ND) {
        const int e    = tid >> 2;
        const int part = tid & 3;
        const float* tv = tgt + (size_t)b * ND + part * 24;
        const float* wr = w2 + e * ND + part * 24;
        float acc = 0.f;
        #pragma unroll
        for (int d = 0; d < 24; d += 4) {
            floatx4 a = *(const floatx4*)(tv + d);
            floatx4 w = *(const floatx4*)(wr + d);
            acc += a[0]*w[0] + a[1]*w[1] + a[2]*w[2] + a[3]*w[3];
        }
        thp4[e][part] = acc;
    }
    __syncthreads();

    float tgtv[6], biasv[6];
    #pragma unroll
    for (int t = 0; t < 6; ++t) {
        const int e = 16 * t + l15;
        floatx4 tp = thp4[e];
        tgtv[t]  = b2[e] + tp[0] + tp[1] + tp[2] + tp[3];
        biasv[t] = b1[e];
    }

    // ---- fused main loop, depth-1 pipelined: consume pre[] (tile sti),
    // immediately issue tile sti+1 loads, then do MFMA/sigmoid/exp/weighted
    // accumulation while they fly. No persistent cross-tile state but pre.
    float o_acc[6] = {0.f, 0.f, 0.f, 0.f, 0.f, 0.f};
    float sacc = 0.f;      // Σ e0 over this quad's rows (dup across l15)

    #pragma unroll
    for (int sti = 0; sti < 4; ++sti) {
        const int s0 = (wave * 4 + sti) * 16;
        short8 af[3];
        af[0] = cvt8(pre[0], pre[1]);
        af[1] = cvt8(pre[2], pre[3]);
        af[2] = cvt8(pre[4], pre[5]);
        if (sti < 3) {   // prefetch next tile
            const float* p = abase + (size_t)(s0 + 16) * ND;
            #pragma unroll
            for (int kk = 0; kk < 3; ++kk) {
                pre[2 * kk]     = *(const floatx4*)(p + kk * 32);
                pre[2 * kk + 1] = *(const floatx4*)(p + kk * 32 + 4);
            }
        }
        floatx4 acc6[6];
        float p0s = 0.f, p1s = 0.f, p2s = 0.f, p3s = 0.f;
        #pragma unroll
        for (int t = 0; t < 6; ++t) {
            floatx4 acc = { biasv[t], biasv[t], biasv[t], biasv[t] };
            #pragma unroll
            for (int kk = 0; kk < 3; ++kk) {
                const short8 bf = *(const short8*)&w1f[((t * 3 + kk) * 64 + lane) * 8];
                acc = __builtin_amdgcn_mfma_f32_16x16x32_bf16(af[kk], bf, acc, 0, 0, 0);
            }
            acc6[t] = acc;
            const float thv = tgtv[t];
            p0s += sigm(acc[0] + thv);
            p1s += sigm(acc[1] + thv);
            p2s += sigm(acc[2] + thv);
            p3s += sigm(acc[3] + thv);
        }
        // reduce over the 16 lanes (e-columns) of each quad; butterfly
        // leaves the full score in every lane of the quad
        #pragma unroll
        for (int off = 1; off < 16; off <<= 1) {
            p0s += __shfl_xor(p0s, off, 64);
            p1s += __shfl_xor(p1s, off, 64);
            p2s += __shfl_xor(p2s, off, 64);
            p3s += __shfl_xor(p3s, off, 64);
        }
        // unnormalized softmax weights for this quad's 4 rows
        // (fixed shift -48: softmax is shift-invariant, scores in (0,96))
        const int sq = s0 + quad * 4;
        const float e0 = maskf[sq + 0] * __expf(p0s - 48.f);
        const float e1 = maskf[sq + 1] * __expf(p1s - 48.f);
        const float e2 = maskf[sq + 2] * __expf(p2s - 48.f);
        const float e3 = maskf[sq + 3] * __expf(p3s - 48.f);
        sacc += e0 + e1 + e2 + e3;
        #pragma unroll
        for (int t = 0; t < 6; ++t) {
            o_acc[t] += e0 * acc6[t][0] + e1 * acc6[t][1]
                      + e2 * acc6[t][2] + e3 * acc6[t][3];
        }
    }

    // ---- denominator: sacc is identical across the 16 l15 lanes of a quad;
    // xor-16/32 sums the 4 quads exactly once ----
    float ss = sacc;
    ss += __shfl_xor(ss, 16, 64);
    ss += __shfl_xor(ss, 32, 64);
    if (lane == 0) red2[wave] = ss;
    __syncthreads();
    float tot = red2[0];
    #pragma unroll
    for (int w = 1; w < 8; ++w) tot += red2[w];

    // ---- output reduce: sum quads in-wave, then waves via LDS ----
    #pragma unroll
    for (int t = 0; t < 6; ++t) {
        o_acc[t] += __shfl_xor(o_acc[t], 16, 64);
        o_acc[t] += __shfl_xor(o_acc[t], 32, 64);
    }
    if (quad == 0) {
        #pragma unroll
        for (int t = 0; t < 6; ++t) osum[wave][16 * t + l15] = o_acc[t];
    }
    __syncthreads();
    if (tid < ND) {
        float a = 0.f;
        #pragma unroll
        for (int w = 0; w < 8; ++w) a += osum[w][tid];
        out[(size_t)b * ND + tid] = a * (1.0f / tot);
    }
}

extern "C" void kernel_launch(void* const* d_in, const int* in_sizes, int n_in,
                              void* d_out, int out_size, void* d_ws, size_t ws_size,
                              hipStream_t stream) {
    const float* seq  = (const float*)d_in[0];
    const float* tgt  = (const float*)d_in[1];
    const int*   mask = (const int*)d_in[2];
    const float* w1   = (const float*)d_in[3];
    const float* b1   = (const float*)d_in[4];
    const float* w2   = (const float*)d_in[5];
    const float* b2   = (const float*)d_in[6];
    float* out = (float*)d_out;
    attn_fused<<<dim3(NB), dim3(512), 0, stream>>>(seq, tgt, mask, w1, b1, w2, b2, out);
}

// Round 6
// 583.638 us; speedup vs baseline: 1.2567x; 1.0201x over previous
//
#include <hip/hip_runtime.h>
#include <math.h>

#define NB 2048
#define NS 512
#define ND 96

typedef __attribute__((ext_vector_type(8))) short short8;
typedef __attribute__((ext_vector_type(4))) float floatx4;

__device__ __forceinline__ float sigm(float x) {
    return 1.0f / (1.0f + __expf(-x));
}
// fp32x8 -> bf16x8 via hardware packed convert (RNE), 4 instructions.
__device__ __forceinline__ short8 cvt8(floatx4 p0, floatx4 p1) {
    union { unsigned u[4]; short8 s; } r;
    asm("v_cvt_pk_bf16_f32 %0, %1, %2" : "=v"(r.u[0]) : "v"(p0[0]), "v"(p0[1]));
    asm("v_cvt_pk_bf16_f32 %0, %1, %2" : "=v"(r.u[1]) : "v"(p0[2]), "v"(p0[3]));
    asm("v_cvt_pk_bf16_f32 %0, %1, %2" : "=v"(r.u[2]) : "v"(p1[0]), "v"(p1[1]));
    asm("v_cvt_pk_bf16_f32 %0, %1, %2" : "=v"(r.u[3]) : "v"(p1[2]), "v"(p1[3]));
    return r.s;
}

// Empirical reg-cap mapping on this toolchain: cap = 2048/(waves_per_block*N).
// (512,4)->64 SPILL, (512,3)->84 SPILL, (512,2)->128 ok (~110 used).
// (256,4) -> cap 128, 4 blocks/CU resident: desynced phases keep HBM busy.
__global__ __launch_bounds__(256, 4)
void attn_fused(const float* __restrict__ seq,   // (B,S,96)
                const float* __restrict__ tgt,   // (B,1,96)
                const int*   __restrict__ mask,  // (B,513,1) int32
                const float* __restrict__ w1,    // (96,96) [e][d]
                const float* __restrict__ b1,    // (96)
                const float* __restrict__ w2,    // (96,96) [e][d]
                const float* __restrict__ b2,    // (96)
                float* __restrict__ out)         // (B,96)
{
    // W1 staged as bf16 MFMA B-fragments: frag(t,kk) for lane L at
    // w1f[((t*3+kk)*64 + L)*8 .. +8]  — ds_read_b128, conflict-free.
    __shared__ short w1f[18 * 64 * 8];           // 18 KB
    __shared__ float thp2[ND][2];                // tgt_h K-halves
    __shared__ float maskf[NS];                  // 1.0 = keep, 0.0 = masked
    __shared__ float red2[4];
    __shared__ float osum[4][ND];                // per-wave output partials

    const int b    = blockIdx.x;
    const int tid  = threadIdx.x;
    const int lane = tid & 63;
    const int wave = tid >> 6;                   // 0..3
    const int l15  = lane & 15;
    const int quad = lane >> 4;

    // ---- mask -> LDS as multiplicative 0/1 float (coalesced) ----
    maskf[tid]       = (mask[(size_t)b * (NS + 1) + tid]       != 0) ? 0.0f : 1.0f;
    maskf[tid + 256] = (mask[(size_t)b * (NS + 1) + tid + 256] != 0) ? 0.0f : 1.0f;

    // ---- stage W1 -> bf16 fragments in LDS ----
    for (int idx = tid; idx < 1152; idx += 256) {   // 96 rows x 12 chunks of 8
        const int e  = idx / 12;
        const int dc = idx - 12 * e;
        const int kk = dc >> 2;
        const int q  = dc & 3;
        const float* p = w1 + e * ND + kk * 32 + q * 8;
        floatx4 p0 = *(const floatx4*)(p);
        floatx4 p1 = *(const floatx4*)(p + 4);
        const int t = e >> 4, r = e & 15;
        *(short8*)&w1f[(((t * 3 + kk) * 64) + q * 16 + r) * 8] = cvt8(p0, p1);
    }

    // ---- tgt_h halves: 192 threads, e = tid>>1, K-half = tid&1 ----
    if (tid < 2 * ND) {
        const int e    = tid >> 1;
        const int part = tid & 1;
        const float* tv = tgt + (size_t)b * ND + part * 48;
        const float* wr = w2 + e * ND + part * 48;
        float acc = 0.f;
        #pragma unroll
        for (int d = 0; d < 48; d += 4) {
            floatx4 a = *(const floatx4*)(tv + d);
            floatx4 w = *(const floatx4*)(wr + d);
            acc += a[0]*w[0] + a[1]*w[1] + a[2]*w[2] + a[3]*w[3];
        }
        thp2[e][part] = acc;
    }
    __syncthreads();

    float tgtv[6], biasv[6];
    #pragma unroll
    for (int t = 0; t < 6; ++t) {
        const int e = 16 * t + l15;
        tgtv[t]  = b2[e] + thp2[e][0] + thp2[e][1];
        biasv[t] = b1[e];
    }

    // ---- fused main loop: each of 4 waves owns 8 s-tiles of 16 rows.
    // Per tile: seq_h via MFMA (fp32 in acc6), scores via sigmoid-sum +
    // quad butterfly, unnormalized weights e = maskf * exp(score-48)
    // (fixed shift; softmax is shift-invariant, scores in (0,96)), and the
    // weighted-output accumulation — no persistent per-tile state.
    const float* abase = seq + ((size_t)b * NS + l15) * ND + quad * 8;
    float o_acc[6] = {0.f, 0.f, 0.f, 0.f, 0.f, 0.f};
    float sacc = 0.f;      // Σ e over this quad's rows (dup across l15)

    #pragma unroll 2
    for (int sti = 0; sti < 8; ++sti) {
        const int s0 = (wave * 8 + sti) * 16;
        short8 af[3];
        #pragma unroll
        for (int kk = 0; kk < 3; ++kk) {
            const float* p = abase + (size_t)s0 * ND + kk * 32;
            af[kk] = cvt8(*(const floatx4*)(p), *(const floatx4*)(p + 4));
        }
        floatx4 acc6[6];
        float p0s = 0.f, p1s = 0.f, p2s = 0.f, p3s = 0.f;
        #pragma unroll
        for (int t = 0; t < 6; ++t) {
            floatx4 acc = { biasv[t], biasv[t], biasv[t], biasv[t] };
            #pragma unroll
            for (int kk = 0; kk < 3; ++kk) {
                const short8 bf = *(const short8*)&w1f[((t * 3 + kk) * 64 + lane) * 8];
                acc = __builtin_amdgcn_mfma_f32_16x16x32_bf16(af[kk], bf, acc, 0, 0, 0);
            }
            acc6[t] = acc;
            const float thv = tgtv[t];
            p0s += sigm(acc[0] + thv);
            p1s += sigm(acc[1] + thv);
            p2s += sigm(acc[2] + thv);
            p3s += sigm(acc[3] + thv);
        }
        // reduce over the 16 lanes (e-columns) of each quad; butterfly
        // leaves the full score in every lane of the quad
        #pragma unroll
        for (int off = 1; off < 16; off <<= 1) {
            p0s += __shfl_xor(p0s, off, 64);
            p1s += __shfl_xor(p1s, off, 64);
            p2s += __shfl_xor(p2s, off, 64);
            p3s += __shfl_xor(p3s, off, 64);
        }
        // unnormalized softmax weights for this quad's 4 rows
        const int sq = s0 + quad * 4;
        const float e0 = maskf[sq + 0] * __expf(p0s - 48.f);
        const float e1 = maskf[sq + 1] * __expf(p1s - 48.f);
        const float e2 = maskf[sq + 2] * __expf(p2s - 48.f);
        const float e3 = maskf[sq + 3] * __expf(p3s - 48.f);
        sacc += e0 + e1 + e2 + e3;
        #pragma unroll
        for (int t = 0; t < 6; ++t) {
            o_acc[t] += e0 * acc6[t][0] + e1 * acc6[t][1]
                      + e2 * acc6[t][2] + e3 * acc6[t][3];
        }
    }

    // ---- denominator: sacc is identical across the 16 l15 lanes of a quad;
    // xor-16/32 sums the 4 quads exactly once ----
    float ss = sacc;
    ss += __shfl_xor(ss, 16, 64);
    ss += __shfl_xor(ss, 32, 64);
    if (lane == 0) red2[wave] = ss;

    // ---- output reduce: sum quads in-wave, then waves via LDS ----
    #pragma unroll
    for (int t = 0; t < 6; ++t) {
        o_acc[t] += __shfl_xor(o_acc[t], 16, 64);
        o_acc[t] += __shfl_xor(o_acc[t], 32, 64);
    }
    if (quad == 0) {
        #pragma unroll
        for (int t = 0; t < 6; ++t) osum[wave][16 * t + l15] = o_acc[t];
    }
    __syncthreads();
    if (tid < ND) {
        const float tot = red2[0] + red2[1] + red2[2] + red2[3];
        float a = 0.f;
        #pragma unroll
        for (int w = 0; w < 4; ++w) a += osum[w][tid];
        out[(size_t)b * ND + tid] = a * (1.0f / tot);
    }
}

extern "C" void kernel_launch(void* const* d_in, const int* in_sizes, int n_in,
                              void* d_out, int out_size, void* d_ws, size_t ws_size,
                              hipStream_t stream) {
    const float* seq  = (const float*)d_in[0];
    const float* tgt  = (const float*)d_in[1];
    const int*   mask = (const int*)d_in[2];
    const float* w1   = (const float*)d_in[3];
    const float* b1   = (const float*)d_in[4];
    const float* w2   = (const float*)d_in[5];
    const float* b2   = (const float*)d_in[6];
    float* out = (float*)d_out;
    attn_fused<<<dim3(NB), dim3(256), 0, stream>>>(seq, tgt, mask, w1, b1, w2, b2, out);
}